// Round 9
// baseline (2891.339 us; speedup 1.0000x reference)
//
#include <hip/hip_runtime.h>
#include <cstddef>

#define Bb 4
#define Ii 4
#define BIc 16
#define Nn 4096
#define Kk 256
#define Dd 128
#define MAXIT 10
#define TOLf 1e-4f
#define KG 8

// ---------------- init kernels ----------------

__global__ __launch_bounds__(64) void init_zero_k(int* done, float* shift, float* inertia) {
    int t = threadIdx.x;
    if (t < BIc) { done[t] = 0; shift[t] = 0.f; inertia[t] = 0.f; }
}

// copy initial centers into ws + compute c2 = sum(c^2) per center row
__global__ __launch_bounds__(128) void init_c_k(const float* __restrict__ cin,
                                                float* __restrict__ c,
                                                float* __restrict__ c2) {
    __shared__ float red[128];
    int g = blockIdx.x;          // bi*K + k
    int t = threadIdx.x;
    float v = cin[(size_t)g * Dd + t];
    c[(size_t)g * Dd + t] = v;
    red[t] = v * v;
    __syncthreads();
    for (int st = 64; st > 0; st >>= 1) { if (t < st) red[t] += red[t + st]; __syncthreads(); }
    if (t == 0) c2[g] = red[0];
}

// x2[b][n] = sum_d x^2 ; one wave per row
__global__ __launch_bounds__(256) void init_x2_k(const float* __restrict__ x,
                                                 float* __restrict__ x2) {
    int r = blockIdx.x * 4 + (threadIdx.x >> 6);   // global row in [0, B*N)
    int lane = threadIdx.x & 63;
    const float* row = x + (size_t)r * Dd;
    float a = row[lane], b2 = row[lane + 64];
    float s = a * a + b2 * b2;
    for (int m = 1; m < 64; m <<= 1) s += __shfl_xor(s, m, 64);
    if (lane == 0) x2[r] = s;
}

// ---------------- assignment (hot) ----------------
// Block: 256 threads = 64 points x 256 centers tile. Thread (pg,cgi):
//   points  p = pg*8 + pp (pp 0..7)
//   centers ci = cgi*4 + cc (cc 0..3) and 128 + cgi*4 + cc (ascending order)
// xs: linear [row][32] (reads are 2-address broadcasts -> no swizzle needed;
//     writes linear b128 conflict-free; reads get base+imm-offset addressing).
// cs: [row][32] with col ^= ((row>>2)&7)<<2 swizzle; all 8 of a thread's c-rows
//     share ONE swz value (cgi&7)<<2, so dd^swz is computed once per dd-iter.
// Software pipeline: cv batch double-buffered one dd-iter ahead (~512 cyc
//     load-use distance), xv one pp ahead. All buffer indices compile-time.
template <int FINAL>
__global__ __launch_bounds__(256, 3)
void assign_k(const float* __restrict__ x, const float* __restrict__ c,
              const float* __restrict__ x2g, const float* __restrict__ c2g,
              int* __restrict__ labels, float* __restrict__ inertia) {
    __shared__ float xs[64 * 32];     // 8 KB
    __shared__ float cs[256 * 32];    // 32 KB
    const int tid  = threadIdx.x;
    const int bi   = blockIdx.x >> 6;
    const int tile = blockIdx.x & 63;
    const int b    = bi >> 2;
    const int n0   = tile * 64;
    const float* xg  = x + ((size_t)b * Nn + n0) * Dd;
    const float* cgl = c + (size_t)bi * Kk * Dd;
    const int pg = tid >> 5, cgi = tid & 31;
    const int xrow = pg * 8;
    const int swz  = (cgi & 7) << 2;   // common col-XOR for all this thread's c rows

#define CSLD(cc, dd) (*(const float4*)&cs[(((cc) < 4 ? (cgi * 4 + (cc)) \
                         : (128 + cgi * 4 + (cc) - 4)) * 32) + ((dd) ^ swz)])
#define XSLD(pp, dd) (*(const float4*)&xs[(xrow + (pp)) * 32 + (dd)])

    float acc[8][8];
#pragma unroll
    for (int i = 0; i < 8; i++)
#pragma unroll
        for (int j = 0; j < 8; j++) acc[i][j] = 0.f;

#pragma unroll 1
    for (int dc = 0; dc < 4; ++dc) {
        __syncthreads();
        {   // stage x tile (linear) + c tile (swizzled), all writes b128 linear
            const int row0 = tid >> 3, colw = (tid & 7) * 4;
#pragma unroll
            for (int p = 0; p < 2; p++) {
                int row = row0 + p * 32;
                float4 v = *(const float4*)(xg + (size_t)row * Dd + dc * 32 + colw);
                *(float4*)&xs[row * 32 + colw] = v;
            }
#pragma unroll
            for (int p = 0; p < 8; p++) {
                int row = row0 + p * 32;
                float4 v = *(const float4*)(cgl + (size_t)row * Dd + dc * 32 + colw);
                int colp = colw ^ (((row >> 2) & 7) << 2);
                *(float4*)&cs[row * 32 + colp] = v;
            }
        }
        __syncthreads();

        float4 cvb[2][8];
        float4 xvb[2];
#pragma unroll
        for (int cc = 0; cc < 8; cc++) cvb[0][cc] = CSLD(cc, 0);
        xvb[0] = XSLD(0, 0);

#pragma unroll
        for (int it = 0; it < 8; ++it) {
            const int dd = it * 4;
            const int cur = it & 1;
            if (it < 7) {
#pragma unroll
                for (int cc = 0; cc < 8; cc++) cvb[cur ^ 1][cc] = CSLD(cc, dd + 4);
            }
#pragma unroll
            for (int pp = 0; pp < 8; ++pp) {
                const int pb = pp & 1;
                if (pp < 7)      xvb[pb ^ 1] = XSLD(pp + 1, dd);
                else if (it < 7) xvb[pb ^ 1] = XSLD(0, dd + 4);
                const float4 xv = xvb[pb];
#pragma unroll
                for (int cc = 0; cc < 8; cc++) {
                    acc[pp][cc] = fmaf(xv.x, cvb[cur][cc].x, acc[pp][cc]);
                    acc[pp][cc] = fmaf(xv.y, cvb[cur][cc].y, acc[pp][cc]);
                    acc[pp][cc] = fmaf(xv.z, cvb[cur][cc].z, acc[pp][cc]);
                    acc[pp][cc] = fmaf(xv.w, cvb[cur][cc].w, acc[pp][cc]);
                }
            }
        }
    }
#undef CSLD
#undef XSLD

    // epilogue: d2 = x2 + c2 - 2*dot ; argmin with first-occurrence tie-break
    // (identical numerics/order to the previously-passing kernel)
    float c2v[8];
#pragma unroll
    for (int cc = 0; cc < 8; cc++) {
        int ci = (cc < 4) ? (cgi * 4 + cc) : (128 + cgi * 4 + cc - 4);
        c2v[cc] = c2g[bi * Kk + ci];
    }
    float isum = 0.f;
#pragma unroll
    for (int pp = 0; pp < 8; pp++) {
        float xp2 = x2g[b * Nn + n0 + pg * 8 + pp];
        float bv = 3.4e38f; int bidx = 0;
#pragma unroll
        for (int cc = 0; cc < 8; cc++) {
            int ci = (cc < 4) ? (cgi * 4 + cc) : (128 + cgi * 4 + cc - 4);
            float d2 = xp2 + c2v[cc] - 2.f * acc[pp][cc];
            if (d2 < bv) { bv = d2; bidx = ci; }
        }
        for (int m = 1; m < 32; m <<= 1) {
            float ov = __shfl_xor(bv, m, 64);
            int   oi = __shfl_xor(bidx, m, 64);
            if (ov < bv || (ov == bv && oi < bidx)) { bv = ov; bidx = oi; }
        }
        if (cgi == 0) {
            labels[bi * Nn + n0 + pg * 8 + pp] = bidx;
            isum += bv;
        }
    }
    if (FINAL && cgi == 0) atomicAdd(&inertia[bi], isum);
}

// ---------------- centroid update (8 centers per block) ----------------
// block = (bi, kgroup of 8 centers). Labels read once -> LDS bytes,
// count -> prefix -> place index lists (uint16), then unrolled gather-sum.
__global__ __launch_bounds__(256)
void update_k(const float* __restrict__ x, float* __restrict__ c,
              float* __restrict__ c2, const int* __restrict__ labels,
              const int* __restrict__ done, float* __restrict__ shift) {
    __shared__ unsigned char  lab8[Nn];       // 4 KB
    __shared__ unsigned short list[Nn];       // 8 KB
    __shared__ int cnt[KG], off[KG], cur[KG];
    __shared__ float red[256];
    const int bi  = blockIdx.x >> 5;          // 32 kgroups per bi
    const int kg0 = (blockIdx.x & 31) * KG;
    if (done[bi]) return;                     // frozen restart keeps c, c2
    const int t = threadIdx.x;
    if (t < KG) cnt[t] = 0;
    const int* lab = labels + bi * Nn;
    __syncthreads();
    for (int i = t; i < Nn; i += 256) lab8[i] = (unsigned char)lab[i];
    __syncthreads();
    for (int i = t; i < Nn; i += 256) {
        int d = (int)lab8[i] - kg0;
        if ((unsigned)d < KG) atomicAdd(&cnt[d], 1);
    }
    __syncthreads();
    if (t == 0) {
        int s = 0;
        for (int j = 0; j < KG; j++) { off[j] = s; cur[j] = s; s += cnt[j]; }
    }
    __syncthreads();
    for (int i = t; i < Nn; i += 256) {
        int d = (int)lab8[i] - kg0;
        if ((unsigned)d < KG) { int p = atomicAdd(&cur[d], 1); list[p] = (unsigned short)i; }
    }
    __syncthreads();

    const int b = bi >> 2;
    const float* xg = x + (size_t)b * Nn * Dd;
    const int col = t & 127, rg = t >> 7;     // 2 row-groups of 128 cols
    float shiftAcc = 0.f;
    for (int j = 0; j < KG; j++) {
        const int k = kg0 + j;
        const int m = cnt[j], o = off[j];
        float* crow = c + ((size_t)bi * Kk + k) * Dd;
        float oldv = crow[col];
        float s0 = 0.f, s1 = 0.f, s2 = 0.f, s3 = 0.f;
        int r = rg;
        for (; r + 6 < m; r += 8) {
            s0 += xg[(size_t)list[o + r    ] * Dd + col];
            s1 += xg[(size_t)list[o + r + 2] * Dd + col];
            s2 += xg[(size_t)list[o + r + 4] * Dd + col];
            s3 += xg[(size_t)list[o + r + 6] * Dd + col];
        }
        for (; r < m; r += 2) s0 += xg[(size_t)list[o + r] * Dd + col];
        red[t] = (s0 + s1) + (s2 + s3);
        __syncthreads();
        if (rg == 0) {
            float tot = red[col] + red[col + 128];
            float nv = (m > 0) ? tot / (float)m : oldv;  // empty keeps old center
            float df = nv - oldv;
            crow[col] = nv;
            red[col] = df * df;
            red[col + 128] = nv * nv;
        }
        __syncthreads();
        for (int st = 64; st > 0; st >>= 1) {
            if (t < st) red[t] += red[t + st];
            else if (t >= 128 && t < 128 + st) red[t] += red[t + st];
            __syncthreads();
        }
        if (t == 0) shiftAcc += red[0];
        if (t == 128) c2[(size_t)bi * Kk + k] = red[128];
        __syncthreads();
    }
    if (t == 0) atomicAdd(&shift[bi], shiftAcc);
}

// done |= shift < TOL (uses pre-update done, same as reference), reset shift
__global__ __launch_bounds__(64) void epi_k(int* done, float* shift) {
    int t = threadIdx.x;
    if (t < BIc) {
        if (!done[t] && shift[t] < TOLf) done[t] = 1;
        shift[t] = 0.f;
    }
}

// ---------------- best-restart selection + output ----------------
__global__ __launch_bounds__(256)
void select_k(const int* __restrict__ labels, const float* __restrict__ c,
              const float* __restrict__ inertia, float* __restrict__ out) {
    __shared__ int sbi; __shared__ float sbv;
    const int b = blockIdx.x;
    if (threadIdx.x == 0) {
        float bv = inertia[b * Ii]; int bidx = 0;
        for (int i = 1; i < Ii; i++) {
            float v = inertia[b * Ii + i];
            if (v < bv) { bv = v; bidx = i; }   // strict <: first occurrence
        }
        sbi = b * Ii + bidx; sbv = bv;
    }
    __syncthreads();
    const int bi = sbi;
    for (int i = threadIdx.x; i < Nn; i += 256)
        out[b * Nn + i] = (float)labels[bi * Nn + i];
    const float* crow = c + (size_t)bi * Kk * Dd;
    float* oc = out + Bb * Nn + (size_t)b * Kk * Dd;
    for (int i = threadIdx.x; i < Kk * Dd; i += 256)
        oc[i] = crow[i];
    if (threadIdx.x == 0) out[Bb * Nn + Bb * Kk * Dd + b] = sbv;
}

// ---------------- launch ----------------
extern "C" void kernel_launch(void* const* d_in, const int* in_sizes, int n_in,
                              void* d_out, int out_size, void* d_ws, size_t ws_size,
                              hipStream_t stream) {
    const float* x   = (const float*)d_in[0];   // (B,N,D) f32
    const float* cin = (const float*)d_in[1];   // (B,I,K,D) f32
    float* out = (float*)d_out;
    float* ws  = (float*)d_ws;

    float* c       = ws;                         // BI*K*D
    float* c2      = c  + (size_t)BIc * Kk * Dd; // BI*K
    float* x2      = c2 + BIc * Kk;              // B*N
    float* shift   = x2 + Bb * Nn;               // BI
    float* inertia = shift + BIc;                // BI
    int*   done    = (int*)(inertia + BIc);      // BI
    int*   labels  = done + BIc;                 // BI*N

    init_zero_k<<<1, 64, 0, stream>>>(done, shift, inertia);
    init_c_k<<<BIc * Kk, 128, 0, stream>>>(cin, c, c2);
    init_x2_k<<<Bb * Nn / 4, 256, 0, stream>>>(x, x2);

    for (int it = 0; it < MAXIT; ++it) {
        assign_k<0><<<BIc * 64, 256, 0, stream>>>(x, c, x2, c2, labels, inertia);
        update_k<<<BIc * 32, 256, 0, stream>>>(x, c, c2, labels, done, shift);
        epi_k<<<1, 64, 0, stream>>>(done, shift);
    }
    assign_k<1><<<BIc * 64, 256, 0, stream>>>(x, c, x2, c2, labels, inertia);
    select_k<<<Bb, 256, 0, stream>>>(labels, c, inertia, out);
}

// Round 11
// 1103.574 us; speedup vs baseline: 2.6200x; 2.6200x over previous
//
#include <hip/hip_runtime.h>
#include <cstddef>

#define Bb 4
#define Ii 4
#define BIc 16
#define Nn 4096
#define Kk 256
#define Dd 128
#define MAXIT 10
#define TOLf 1e-4f
#define KG 8

// ---------------- init kernels ----------------

__global__ __launch_bounds__(64) void init_zero_k(int* done, float* shift, float* inertia) {
    int t = threadIdx.x;
    if (t < BIc) { done[t] = 0; shift[t] = 0.f; inertia[t] = 0.f; }
}

// copy initial centers into ws + compute c2 = sum(c^2) per center row
__global__ __launch_bounds__(128) void init_c_k(const float* __restrict__ cin,
                                                float* __restrict__ c,
                                                float* __restrict__ c2) {
    __shared__ float red[128];
    int g = blockIdx.x;          // bi*K + k
    int t = threadIdx.x;
    float v = cin[(size_t)g * Dd + t];
    c[(size_t)g * Dd + t] = v;
    red[t] = v * v;
    __syncthreads();
    for (int st = 64; st > 0; st >>= 1) { if (t < st) red[t] += red[t + st]; __syncthreads(); }
    if (t == 0) c2[g] = red[0];
}

// x2[b][n] = sum_d x^2 ; one wave per row
__global__ __launch_bounds__(256) void init_x2_k(const float* __restrict__ x,
                                                 float* __restrict__ x2) {
    int r = blockIdx.x * 4 + (threadIdx.x >> 6);   // global row in [0, B*N)
    int lane = threadIdx.x & 63;
    const float* row = x + (size_t)r * Dd;
    float a = row[lane], b2 = row[lane + 64];
    float s = a * a + b2 * b2;
    for (int m = 1; m < 64; m <<= 1) s += __shfl_xor(s, m, 64);
    if (lane == 0) x2[r] = s;
}

// ---------------- assignment (hot) ----------------
// Block: 256 threads = 64 points x 256 centers tile. Thread (pg,cgi):
//   points  p = pg*8 + pp ; centers ci = cgi*4 + cc and 128 + cgi*4 + cc.
// xs: linear [row][32]  (xv reads are 2-address broadcasts; writes linear b128)
// cs: [row][32], col ^= ((row>>2)&7)<<2 ; all 8 c-rows of a thread share swz.
// Pipeline: cv double-buffered via NAMED arrays cvA/cvB with hand-unrolled
// alternation (all indices compile-time -> registers, no scratch). Next-dd
// loads issue BEFORE the current FMA block so LDS latency hides under FMAs.
// __launch_bounds__(256,2): VGPR cap 256 (fits acc64+cv64+xv8+addr; round-9's
// cap of 168 caused a 550MB/dispatch scratch spill = the 256us regression).
template <int FINAL>
__global__ __launch_bounds__(256, 2)
void assign_k(const float* __restrict__ x, const float* __restrict__ c,
              const float* __restrict__ x2g, const float* __restrict__ c2g,
              int* __restrict__ labels, float* __restrict__ inertia) {
    __shared__ float xs[64 * 32];     // 8 KB
    __shared__ float cs[256 * 32];    // 32 KB
    const int tid  = threadIdx.x;
    const int bi   = blockIdx.x >> 6;
    const int tile = blockIdx.x & 63;
    const int b    = bi >> 2;
    const int n0   = tile * 64;
    const float* xg  = x + ((size_t)b * Nn + n0) * Dd;
    const float* cgl = c + (size_t)bi * Kk * Dd;
    const int pg = tid >> 5, cgi = tid & 31;
    const int xrow = pg * 8;
    const int swz  = (cgi & 7) << 2;   // common col-XOR for all this thread's c rows

#define CSLD(cc, dd) (*(const float4*)&cs[(((cc) < 4 ? (cgi * 4 + (cc)) \
                         : (128 + cgi * 4 + (cc) - 4)) * 32) + ((dd) ^ swz)])
#define XSLD(pp, dd) (*(const float4*)&xs[(xrow + (pp)) * 32 + (dd)])

#define LOADCV(BUF, dd) do { \
    BUF[0] = CSLD(0, dd); BUF[1] = CSLD(1, dd); BUF[2] = CSLD(2, dd); BUF[3] = CSLD(3, dd); \
    BUF[4] = CSLD(4, dd); BUF[5] = CSLD(5, dd); BUF[6] = CSLD(6, dd); BUF[7] = CSLD(7, dd); \
} while (0)

#define DOFMA(BUF, dd, prefX) do { \
    _Pragma("unroll") \
    for (int pp = 0; pp < 8; ++pp) { \
        const int pb = pp & 1; \
        if (pp < 7)       xvb[pb ^ 1] = XSLD(pp + 1, dd); \
        else if (prefX)   xvb[pb ^ 1] = XSLD(0, (dd) + 4); \
        const float4 xv = xvb[pb]; \
        _Pragma("unroll") \
        for (int cc = 0; cc < 8; cc++) { \
            acc[pp][cc] = fmaf(xv.x, BUF[cc].x, acc[pp][cc]); \
            acc[pp][cc] = fmaf(xv.y, BUF[cc].y, acc[pp][cc]); \
            acc[pp][cc] = fmaf(xv.z, BUF[cc].z, acc[pp][cc]); \
            acc[pp][cc] = fmaf(xv.w, BUF[cc].w, acc[pp][cc]); \
        } \
    } \
} while (0)

    float acc[8][8];
#pragma unroll
    for (int i = 0; i < 8; i++)
#pragma unroll
        for (int j = 0; j < 8; j++) acc[i][j] = 0.f;

#pragma unroll 1
    for (int dc = 0; dc < 4; ++dc) {
        __syncthreads();
        {   // stage x tile (linear) + c tile (swizzled), all writes b128 linear
            const int row0 = tid >> 3, colw = (tid & 7) * 4;
#pragma unroll
            for (int p = 0; p < 2; p++) {
                int row = row0 + p * 32;
                float4 v = *(const float4*)(xg + (size_t)row * Dd + dc * 32 + colw);
                *(float4*)&xs[row * 32 + colw] = v;
            }
#pragma unroll
            for (int p = 0; p < 8; p++) {
                int row = row0 + p * 32;
                float4 v = *(const float4*)(cgl + (size_t)row * Dd + dc * 32 + colw);
                int colp = colw ^ (((row >> 2) & 7) << 2);
                *(float4*)&cs[row * 32 + colp] = v;
            }
        }
        __syncthreads();

        float4 cvA[8], cvB[8], xvb[2];
        LOADCV(cvA, 0);
        xvb[0] = XSLD(0, 0);

        LOADCV(cvB, 4);   DOFMA(cvA, 0, 1);
        LOADCV(cvA, 8);   DOFMA(cvB, 4, 1);
        LOADCV(cvB, 12);  DOFMA(cvA, 8, 1);
        LOADCV(cvA, 16);  DOFMA(cvB, 12, 1);
        LOADCV(cvB, 20);  DOFMA(cvA, 16, 1);
        LOADCV(cvA, 24);  DOFMA(cvB, 20, 1);
        LOADCV(cvB, 28);  DOFMA(cvA, 24, 1);
                          DOFMA(cvB, 28, 0);
    }
#undef LOADCV
#undef DOFMA
#undef CSLD
#undef XSLD

    // epilogue: d2 = x2 + c2 - 2*dot ; argmin with first-occurrence tie-break
    // (identical numerics/order to the previously-passing kernel)
    float c2v[8];
#pragma unroll
    for (int cc = 0; cc < 8; cc++) {
        int ci = (cc < 4) ? (cgi * 4 + cc) : (128 + cgi * 4 + cc - 4);
        c2v[cc] = c2g[bi * Kk + ci];
    }
    float isum = 0.f;
#pragma unroll
    for (int pp = 0; pp < 8; pp++) {
        float xp2 = x2g[b * Nn + n0 + pg * 8 + pp];
        float bv = 3.4e38f; int bidx = 0;
#pragma unroll
        for (int cc = 0; cc < 8; cc++) {
            int ci = (cc < 4) ? (cgi * 4 + cc) : (128 + cgi * 4 + cc - 4);
            float d2 = xp2 + c2v[cc] - 2.f * acc[pp][cc];
            if (d2 < bv) { bv = d2; bidx = ci; }
        }
        for (int m = 1; m < 32; m <<= 1) {
            float ov = __shfl_xor(bv, m, 64);
            int   oi = __shfl_xor(bidx, m, 64);
            if (ov < bv || (ov == bv && oi < bidx)) { bv = ov; bidx = oi; }
        }
        if (cgi == 0) {
            labels[bi * Nn + n0 + pg * 8 + pp] = bidx;
            isum += bv;
        }
    }
    if (FINAL && cgi == 0) atomicAdd(&inertia[bi], isum);
}

// ---------------- centroid update (8 centers per block) ----------------
// block = (bi, kgroup of 8 centers). Labels read once -> LDS bytes,
// count -> prefix -> place index lists (uint16), then unrolled gather-sum.
__global__ __launch_bounds__(256)
void update_k(const float* __restrict__ x, float* __restrict__ c,
              float* __restrict__ c2, const int* __restrict__ labels,
              const int* __restrict__ done, float* __restrict__ shift) {
    __shared__ unsigned char  lab8[Nn];       // 4 KB
    __shared__ unsigned short list[Nn];       // 8 KB
    __shared__ int cnt[KG], off[KG], cur[KG];
    __shared__ float red[256];
    const int bi  = blockIdx.x >> 5;          // 32 kgroups per bi
    const int kg0 = (blockIdx.x & 31) * KG;
    if (done[bi]) return;                     // frozen restart keeps c, c2
    const int t = threadIdx.x;
    if (t < KG) cnt[t] = 0;
    const int* lab = labels + bi * Nn;
    __syncthreads();
    for (int i = t; i < Nn; i += 256) lab8[i] = (unsigned char)lab[i];
    __syncthreads();
    for (int i = t; i < Nn; i += 256) {
        int d = (int)lab8[i] - kg0;
        if ((unsigned)d < KG) atomicAdd(&cnt[d], 1);
    }
    __syncthreads();
    if (t == 0) {
        int s = 0;
        for (int j = 0; j < KG; j++) { off[j] = s; cur[j] = s; s += cnt[j]; }
    }
    __syncthreads();
    for (int i = t; i < Nn; i += 256) {
        int d = (int)lab8[i] - kg0;
        if ((unsigned)d < KG) { int p = atomicAdd(&cur[d], 1); list[p] = (unsigned short)i; }
    }
    __syncthreads();

    const int b = bi >> 2;
    const float* xg = x + (size_t)b * Nn * Dd;
    const int col = t & 127, rg = t >> 7;     // 2 row-groups of 128 cols
    float shiftAcc = 0.f;
    for (int j = 0; j < KG; j++) {
        const int k = kg0 + j;
        const int m = cnt[j], o = off[j];
        float* crow = c + ((size_t)bi * Kk + k) * Dd;
        float oldv = crow[col];
        float s0 = 0.f, s1 = 0.f, s2 = 0.f, s3 = 0.f;
        int r = rg;
        for (; r + 6 < m; r += 8) {
            s0 += xg[(size_t)list[o + r    ] * Dd + col];
            s1 += xg[(size_t)list[o + r + 2] * Dd + col];
            s2 += xg[(size_t)list[o + r + 4] * Dd + col];
            s3 += xg[(size_t)list[o + r + 6] * Dd + col];
        }
        for (; r < m; r += 2) s0 += xg[(size_t)list[o + r] * Dd + col];
        red[t] = (s0 + s1) + (s2 + s3);
        __syncthreads();
        if (rg == 0) {
            float tot = red[col] + red[col + 128];
            float nv = (m > 0) ? tot / (float)m : oldv;  // empty keeps old center
            float df = nv - oldv;
            crow[col] = nv;
            red[col] = df * df;
            red[col + 128] = nv * nv;
        }
        __syncthreads();
        for (int st = 64; st > 0; st >>= 1) {
            if (t < st) red[t] += red[t + st];
            else if (t >= 128 && t < 128 + st) red[t] += red[t + st];
            __syncthreads();
        }
        if (t == 0) shiftAcc += red[0];
        if (t == 128) c2[(size_t)bi * Kk + k] = red[128];
        __syncthreads();
    }
    if (t == 0) atomicAdd(&shift[bi], shiftAcc);
}

// done |= shift < TOL (uses pre-update done, same as reference), reset shift
__global__ __launch_bounds__(64) void epi_k(int* done, float* shift) {
    int t = threadIdx.x;
    if (t < BIc) {
        if (!done[t] && shift[t] < TOLf) done[t] = 1;
        shift[t] = 0.f;
    }
}

// ---------------- best-restart selection + output ----------------
__global__ __launch_bounds__(256)
void select_k(const int* __restrict__ labels, const float* __restrict__ c,
              const float* __restrict__ inertia, float* __restrict__ out) {
    __shared__ int sbi; __shared__ float sbv;
    const int b = blockIdx.x;
    if (threadIdx.x == 0) {
        float bv = inertia[b * Ii]; int bidx = 0;
        for (int i = 1; i < Ii; i++) {
            float v = inertia[b * Ii + i];
            if (v < bv) { bv = v; bidx = i; }   // strict <: first occurrence
        }
        sbi = b * Ii + bidx; sbv = bv;
    }
    __syncthreads();
    const int bi = sbi;
    for (int i = threadIdx.x; i < Nn; i += 256)
        out[b * Nn + i] = (float)labels[bi * Nn + i];
    const float* crow = c + (size_t)bi * Kk * Dd;
    float* oc = out + Bb * Nn + (size_t)b * Kk * Dd;
    for (int i = threadIdx.x; i < Kk * Dd; i += 256)
        oc[i] = crow[i];
    if (threadIdx.x == 0) out[Bb * Nn + Bb * Kk * Dd + b] = sbv;
}

// ---------------- launch ----------------
extern "C" void kernel_launch(void* const* d_in, const int* in_sizes, int n_in,
                              void* d_out, int out_size, void* d_ws, size_t ws_size,
                              hipStream_t stream) {
    const float* x   = (const float*)d_in[0];   // (B,N,D) f32
    const float* cin = (const float*)d_in[1];   // (B,I,K,D) f32
    float* out = (float*)d_out;
    float* ws  = (float*)d_ws;

    float* c       = ws;                         // BI*K*D
    float* c2      = c  + (size_t)BIc * Kk * Dd; // BI*K
    float* x2      = c2 + BIc * Kk;              // B*N
    float* shift   = x2 + Bb * Nn;               // BI
    float* inertia = shift + BIc;                // BI
    int*   done    = (int*)(inertia + BIc);      // BI
    int*   labels  = done + BIc;                 // BI*N

    init_zero_k<<<1, 64, 0, stream>>>(done, shift, inertia);
    init_c_k<<<BIc * Kk, 128, 0, stream>>>(cin, c, c2);
    init_x2_k<<<Bb * Nn / 4, 256, 0, stream>>>(x, x2);

    for (int it = 0; it < MAXIT; ++it) {
        assign_k<0><<<BIc * 64, 256, 0, stream>>>(x, c, x2, c2, labels, inertia);
        update_k<<<BIc * 32, 256, 0, stream>>>(x, c, c2, labels, done, shift);
        epi_k<<<1, 64, 0, stream>>>(done, shift);
    }
    assign_k<1><<<BIc * 64, 256, 0, stream>>>(x, c, x2, c2, labels, inertia);
    select_k<<<Bb, 256, 0, stream>>>(labels, c, inertia, out);
}